// Round 6
// baseline (161.897 us; speedup 1.0000x reference)
//
#include <hip/hip_runtime.h>

typedef __attribute__((ext_vector_type(8))) short bf16x8;   // 8 bf16 in 4 VGPRs
typedef __attribute__((ext_vector_type(4))) float f32x4;

#define BLK   256
#define NWAVE 4
#define NPT   16      // points per wave-tile
#define MAXB  1024    // 4 blocks/CU -> 16 waves/CU = 4 waves/SIMD at <=128 regs

union U4 { uint4 u; bf16x8 v; };

// tanh(x) = 1 - 2/(exp(2x)+1); ~1 ulp, saturates correctly.
__device__ __forceinline__ float tanh_fast(float v) {
    float e = __builtin_amdgcn_exp2f(v * 2.8853900817779268f);
    float r = __builtin_amdgcn_rcpf(e + 1.0f);
    return fmaf(-2.0f, r, 1.0f);
}

// {bf16(a) in low16, bf16(b) in high16} (truncation) = one v_perm_b32.
__device__ __forceinline__ unsigned int packlohi(unsigned int a, unsigned int b) {
    return __builtin_amdgcn_perm(b, a, 0x07060302u);
}

// Split 8 fp32 into bf16 hi (truncate) + lo (residual) register fragments.
__device__ __forceinline__ void pack8(const float* v, bf16x8* hi, bf16x8* lo) {
    unsigned int hb[8], lb[8];
#pragma unroll
    for (int j = 0; j < 8; ++j) {
        const unsigned int bits = __float_as_uint(v[j]);
        const unsigned int h = bits & 0xffff0000u;
        hb[j] = h;
        lb[j] = __float_as_uint(v[j] - __uint_as_float(h));
    }
    U4 uh, ul;
    uh.u = make_uint4(packlohi(hb[0],hb[1]), packlohi(hb[2],hb[3]),
                      packlohi(hb[4],hb[5]), packlohi(hb[6],hb[7]));
    ul.u = make_uint4(packlohi(lb[0],lb[1]), packlohi(lb[2],lb[3]),
                      packlohi(lb[4],lb[5]), packlohi(lb[6],lb[7]));
    *hi = uh.v;
    *lo = ul.v;
}

#define MFMA __builtin_amdgcn_mfma_f32_16x16x32_bf16

// Barrier-free GEMM-ified curl, register-trimmed so the TRUE live set fits in
// 128 VGPRs (no AGPR parking / v_accvgpr copy traffic — the round-5 2.3x VALU
// bloat). W1/b1 now live in LDS (bank-disjoint broadcast reads) instead of 64
// loop-invariant VGPRs. Shared k-permutation kappa(q,kc,j)=q*16+kc*8+j for both
// MFMA operands cancels in the contraction; B fragments are exactly what each
// lane computes in layer 1 for its own point. C/D: col=lane&15=p,
// row=(lane>>4)*4+reg -> h=m*16+q*4+r; epilogue fully lane-local.
__global__ __launch_bounds__(BLK, 4) void curl_mfma(
    const float* __restrict__ x,  const float* __restrict__ W1,
    const float* __restrict__ b1, const float* __restrict__ W2,
    const float* __restrict__ b2, const float* __restrict__ W3,
    float* __restrict__ out, int npts, int iters, int ntiles)
{
    // sW1 slot perm ((k&15)<<2)|(k>>4): the 4 simultaneous q-addresses of one
    // (kc,j) read land on 4 consecutive float4 slots -> 16 distinct banks.
    __shared__ float4 sW1[64];    // {W1[k,0], W1[k,1], W1[k,2], b1[k]} — 1 KiB
    __shared__ float4 sLUT[64];   // {b2[h], W3[0][h], W3[1][h], W3[2][h]} — 1 KiB

    const int tid  = threadIdx.x;
    const int wv   = tid >> 6;
    const int lane = tid & 63;
    const int p    = lane & 15;   // point-in-tile == B col == D col
    const int q    = lane >> 4;   // k-group (kappa) and h-subgroup of D

    if (tid < 64) {
        sLUT[tid] = make_float4(b2[tid], W3[tid], W3[64 + tid], W3[128 + tid]);
        sW1[((tid & 15) << 2) | (tid >> 4)] =
            make_float4(W1[tid * 3 + 0], W1[tid * 3 + 1], W1[tid * 3 + 2], b1[tid]);
    }

    // A fragments (once per wave): W2 row m*16+p, k = kappa(q,kc,j) = q*16+kc*8+j.
    bf16x8 Ahi[4][2], Alo[4][2];
#pragma unroll
    for (int m = 0; m < 4; ++m)
#pragma unroll
        for (int kc = 0; kc < 2; ++kc) {
            const float* src = W2 + (m * 16 + p) * 64 + q * 16 + kc * 8;
            const float4 va = ((const float4*)src)[0];
            const float4 vb = ((const float4*)src)[1];
            const float vv[8] = {va.x, va.y, va.z, va.w, vb.x, vb.y, vb.z, vb.w};
            pack8(vv, &Ahi[m][kc], &Alo[m][kc]);
        }
    __syncthreads();   // tables ready; no barriers after this point

    const int gw = blockIdx.x * NWAVE + wv;
    const int nw = gridDim.x * NWAVE;

    for (int it = 0; it < iters; ++it) {
        const int tile = gw + it * nw;
        if (tile >= ntiles) break;         // no barriers -> divergent exit is safe
        const int id = tile * NPT + p;

        float x0 = 0.f, x1 = 0.f, x2 = 0.f;
        if (id < npts) {
            x0 = x[id * 3 + 0];
            x1 = x[id * 3 + 1];
            x2 = x[id * 3 + 2];
        }

        // ---- Layer 1 + g = D1*W1col; pack straight into B register fragments ----
        bf16x8 Bhi[4][2], Blo[4][2];       // [type][kc]
#pragma unroll
        for (int kc = 0; kc < 2; ++kc) {
            float vh[8], v0[8], v1[8], v2[8];
#pragma unroll
            for (int j = 0; j < 8; ++j) {
                const float4 w = sW1[(((kc * 8 + j) & 15) << 2) | q];  // k=q*16+kc*8+j
                float a = fmaf(w.x, x0, w.w);
                a = fmaf(w.y, x1, a);
                a = fmaf(w.z, x2, a);
                const float th = tanh_fast(a);
                const float d1 = fmaf(-th, th, 1.0f);
                vh[j] = th;
                v0[j] = d1 * w.x;
                v1[j] = d1 * w.y;
                v2[j] = d1 * w.z;
            }
            pack8(vh, &Bhi[0][kc], &Blo[0][kc]);
            pack8(v0, &Bhi[1][kc], &Blo[1][kc]);
            pack8(v1, &Bhi[2][kc], &Blo[2][kc]);
            pack8(v2, &Bhi[3][kc], &Blo[3][kc]);
        }

        // ---- MFMA: 4 M-tiles x 2 k-chunks x 3 split-terms x 4 types = 96 ----
        float c0 = 0.f, c1 = 0.f, c2 = 0.f;
#pragma unroll
        for (int m = 0; m < 4; ++m) {
            f32x4 a0 = {0.f,0.f,0.f,0.f}, a1 = a0, a2 = a0, a3 = a0;
#pragma unroll
            for (int kc = 0; kc < 2; ++kc) {
                a0 = MFMA(Ahi[m][kc], Bhi[0][kc], a0, 0, 0, 0);
                a1 = MFMA(Ahi[m][kc], Bhi[1][kc], a1, 0, 0, 0);
                a2 = MFMA(Ahi[m][kc], Bhi[2][kc], a2, 0, 0, 0);
                a3 = MFMA(Ahi[m][kc], Bhi[3][kc], a3, 0, 0, 0);
                a0 = MFMA(Ahi[m][kc], Blo[0][kc], a0, 0, 0, 0);
                a1 = MFMA(Ahi[m][kc], Blo[1][kc], a1, 0, 0, 0);
                a2 = MFMA(Ahi[m][kc], Blo[2][kc], a2, 0, 0, 0);
                a3 = MFMA(Ahi[m][kc], Blo[3][kc], a3, 0, 0, 0);
                a0 = MFMA(Alo[m][kc], Bhi[0][kc], a0, 0, 0, 0);
                a1 = MFMA(Alo[m][kc], Bhi[1][kc], a1, 0, 0, 0);
                a2 = MFMA(Alo[m][kc], Bhi[2][kc], a2, 0, 0, 0);
                a3 = MFMA(Alo[m][kc], Bhi[3][kc], a3, 0, 0, 0);
            }
            // Epilogue for h = m*16 + q*4 + r (a0=s0pre, a1=u0, a2=u1, a3=u2)
#pragma unroll
            for (int r = 0; r < 4; ++r) {
                const float4 lut = sLUT[m*16 + q*4 + r];
                const float s0 = a0[r] + lut.x;
                const float th = tanh_fast(s0);
                const float d2 = fmaf(-th, th, 1.0f);
                const float e0 = lut.y * d2, e1 = lut.z * d2, e2 = lut.w * d2;
                c0 = fmaf(e2, a2[r], c0); c0 = fmaf(-e1, a3[r], c0);
                c1 = fmaf(e0, a3[r], c1); c1 = fmaf(-e2, a1[r], c1);
                c2 = fmaf(e1, a1[r], c2); c2 = fmaf(-e0, a2[r], c2);
            }
        }

        // Reduce partial curls over the 4 h-subgroups (q dimension).
        c0 += __shfl_xor(c0, 16); c0 += __shfl_xor(c0, 32);
        c1 += __shfl_xor(c1, 16); c1 += __shfl_xor(c1, 32);
        c2 += __shfl_xor(c2, 16); c2 += __shfl_xor(c2, 32);

        // Coalesced store: lane (p,q<3) writes component q of point p ->
        // 48 contiguous dwords per tile.
        if (q < 3 && id < npts) {
            const float cv = (q == 0) ? c0 : ((q == 1) ? c1 : c2);
            out[tile * (NPT * 3) + p * 3 + q] = cv;
        }
    }
}

extern "C" void kernel_launch(void* const* d_in, const int* in_sizes, int n_in,
                              void* d_out, int out_size, void* d_ws, size_t ws_size,
                              hipStream_t stream) {
    const float* x  = (const float*)d_in[0];
    const float* W1 = (const float*)d_in[1];
    const float* b1 = (const float*)d_in[2];
    const float* W2 = (const float*)d_in[3];
    const float* b2 = (const float*)d_in[4];
    const float* W3 = (const float*)d_in[5];
    // d_in[6] (b3) unused: it cancels in the Jacobian.
    float* out = (float*)d_out;

    const int npts   = in_sizes[0] / 3;
    const int ntiles = (npts + NPT - 1) / NPT;
    int blocks = (ntiles + NWAVE - 1) / NWAVE;
    if (blocks > MAXB) blocks = MAXB;
    const int nw    = blocks * NWAVE;
    const int iters = (ntiles + nw - 1) / nw;

    hipLaunchKernelGGL(curl_mfma, dim3(blocks), dim3(BLK), 0, stream,
                       x, W1, b1, W2, b2, W3, out, npts, iters, ntiles);
}

// Round 7
// 130.615 us; speedup vs baseline: 1.2395x; 1.2395x over previous
//
#include <hip/hip_runtime.h>

typedef __attribute__((ext_vector_type(8))) short bf16x8;   // 8 bf16 in 4 VGPRs
typedef __attribute__((ext_vector_type(4))) float f32x4;

#define BLK   256
#define NWAVE 4
#define NPT   16      // points per wave-tile
#define MAXB  1024    // 4 blocks/CU; occupancy goal 4 waves/SIMD at <=128 VGPR

union U4 { uint4 u; bf16x8 v; };

// tanh(x) = 1 - 2/(exp(2x)+1); ~1 ulp, saturates correctly.
__device__ __forceinline__ float tanh_fast(float v) {
    float e = __builtin_amdgcn_exp2f(v * 2.8853900817779268f);
    float r = __builtin_amdgcn_rcpf(e + 1.0f);
    return fmaf(-2.0f, r, 1.0f);
}

// {bf16(a) in low16, bf16(b) in high16} (truncation) = one v_perm_b32.
__device__ __forceinline__ unsigned int packlohi(unsigned int a, unsigned int b) {
    return __builtin_amdgcn_perm(b, a, 0x07060302u);
}

// Split 8 fp32 into bf16 hi (truncate) + lo (residual) register fragments.
__device__ __forceinline__ void pack8(const float* v, bf16x8* hi, bf16x8* lo) {
    unsigned int hb[8], lb[8];
#pragma unroll
    for (int j = 0; j < 8; ++j) {
        const unsigned int bits = __float_as_uint(v[j]);
        const unsigned int h = bits & 0xffff0000u;
        hb[j] = h;
        lb[j] = __float_as_uint(v[j] - __uint_as_float(h));
    }
    U4 uh, ul;
    uh.u = make_uint4(packlohi(hb[0],hb[1]), packlohi(hb[2],hb[3]),
                      packlohi(hb[4],hb[5]), packlohi(hb[6],hb[7]));
    ul.u = make_uint4(packlohi(lb[0],lb[1]), packlohi(lb[2],lb[3]),
                      packlohi(lb[4],lb[5]), packlohi(lb[6],lb[7]));
    *hi = uh.v;
    *lo = ul.v;
}

#define MFMA __builtin_amdgcn_mfma_f32_16x16x32_bf16

// Round-7 change: A fragments (identical for every wave — lane-dependent only)
// move from 64 loop-invariant VGPRs into 16 KiB LDS, streamed per-m inside a
// no-unroll m-loop (16 A-regs live at a time). True live set ~111 < 128 ->
// no AGPR parking / no spill, 4 waves/SIMD resident (grid = 4 blocks/CU).
// kappa(q,kc,j)=q*16+kc*8+j shared by A and B cancels in the contraction; B
// fragments are exactly what each lane computes in layer 1 for its own point.
// C/D: col=lane&15=p, row=(lane>>4)*4+reg -> h=m*16+q*4+r; epilogue lane-local.
__global__ __launch_bounds__(BLK, 2) void curl_mfma(
    const float* __restrict__ x,  const float* __restrict__ W1,
    const float* __restrict__ b1, const float* __restrict__ W2,
    const float* __restrict__ b2, const float* __restrict__ W3,
    float* __restrict__ out, int npts, int iters, int ntiles)
{
    // sA[((m*2+kc)*2+plane)*64 + lane]: packed A fragment (plane 0 = hi, 1 = lo).
    // Per-lane consecutive 16B -> conflict-free ds_read/ds_write.
    __shared__ uint4  sA[16 * 64];   // 16 KiB
    __shared__ float4 sW1[64];       // {W1[k,0..2], b1[k]}, slot-permuted — 1 KiB
    __shared__ float4 sLUT[64];      // {b2[h], W3[0][h], W3[1][h], W3[2][h]} — 1 KiB

    const int tid  = threadIdx.x;
    const int wv   = tid >> 6;
    const int lane = tid & 63;
    const int p    = lane & 15;   // point-in-tile == B col == D col
    const int q    = lane >> 4;   // k-group (kappa) and h-subgroup of D

    if (tid < 64) {
        sLUT[tid] = make_float4(b2[tid], W3[tid], W3[64 + tid], W3[128 + tid]);
        sW1[((tid & 15) << 2) | (tid >> 4)] =
            make_float4(W1[tid * 3 + 0], W1[tid * 3 + 1], W1[tid * 3 + 2], b1[tid]);
    }

    // Wave wv builds the A fragments for m = wv (W2 row m*16+p, k = kappa(q,kc,j)).
    {
        const int m = wv;
#pragma unroll
        for (int kc = 0; kc < 2; ++kc) {
            const float* src = W2 + (m * 16 + p) * 64 + q * 16 + kc * 8;
            const float4 va = ((const float4*)src)[0];
            const float4 vb = ((const float4*)src)[1];
            const float vv[8] = {va.x, va.y, va.z, va.w, vb.x, vb.y, vb.z, vb.w};
            bf16x8 hi, lo;
            pack8(vv, &hi, &lo);
            U4 uh, ul; uh.v = hi; ul.v = lo;
            sA[((m * 2 + kc) * 2 + 0) * 64 + lane] = uh.u;
            sA[((m * 2 + kc) * 2 + 1) * 64 + lane] = ul.u;
        }
    }
    __syncthreads();   // tables ready; no barriers after this point

    const int gw = blockIdx.x * NWAVE + wv;
    const int nw = gridDim.x * NWAVE;

    for (int it = 0; it < iters; ++it) {
        const int tile = gw + it * nw;
        if (tile >= ntiles) break;         // no barriers -> divergent exit is safe
        const int id = tile * NPT + p;

        float x0 = 0.f, x1 = 0.f, x2 = 0.f;
        if (id < npts) {
            x0 = x[id * 3 + 0];
            x1 = x[id * 3 + 1];
            x2 = x[id * 3 + 2];
        }

        // ---- Layer 1 + g = D1*W1col; pack straight into B register fragments ----
        bf16x8 Bhi[4][2], Blo[4][2];       // [type][kc] — 64 VGPRs, live all tile
#pragma unroll
        for (int kc = 0; kc < 2; ++kc) {
            float vh[8], v0[8], v1[8], v2[8];
#pragma unroll
            for (int j = 0; j < 8; ++j) {
                const float4 w = sW1[(((kc * 8 + j) & 15) << 2) | q];  // k=q*16+kc*8+j
                float a = fmaf(w.x, x0, w.w);
                a = fmaf(w.y, x1, a);
                a = fmaf(w.z, x2, a);
                const float th = tanh_fast(a);
                const float d1 = fmaf(-th, th, 1.0f);
                vh[j] = th;
                v0[j] = d1 * w.x;
                v1[j] = d1 * w.y;
                v2[j] = d1 * w.z;
            }
            pack8(vh, &Bhi[0][kc], &Blo[0][kc]);
            pack8(v0, &Bhi[1][kc], &Blo[1][kc]);
            pack8(v1, &Bhi[2][kc], &Blo[2][kc]);
            pack8(v2, &Bhi[3][kc], &Blo[3][kc]);
        }

        // ---- MFMA: m streamed from LDS (16 A-regs live), 24 MFMA per m ----
        float c0 = 0.f, c1 = 0.f, c2 = 0.f;
#pragma unroll 1
        for (int m = 0; m < 4; ++m) {
            U4 Ah0, Al0, Ah1, Al1;                   // A for this m only
            const uint4* pA = &sA[(m * 4) * 64 + lane];
            Ah0.u = pA[0 * 64];                      // kc0 hi
            Al0.u = pA[1 * 64];                      // kc0 lo
            Ah1.u = pA[2 * 64];                      // kc1 hi
            Al1.u = pA[3 * 64];                      // kc1 lo

            f32x4 a0 = {0.f,0.f,0.f,0.f}, a1 = a0, a2 = a0, a3 = a0;
            // kc = 0
            a0 = MFMA(Ah0.v, Bhi[0][0], a0, 0, 0, 0);
            a1 = MFMA(Ah0.v, Bhi[1][0], a1, 0, 0, 0);
            a2 = MFMA(Ah0.v, Bhi[2][0], a2, 0, 0, 0);
            a3 = MFMA(Ah0.v, Bhi[3][0], a3, 0, 0, 0);
            a0 = MFMA(Ah0.v, Blo[0][0], a0, 0, 0, 0);
            a1 = MFMA(Ah0.v, Blo[1][0], a1, 0, 0, 0);
            a2 = MFMA(Ah0.v, Blo[2][0], a2, 0, 0, 0);
            a3 = MFMA(Ah0.v, Blo[3][0], a3, 0, 0, 0);
            a0 = MFMA(Al0.v, Bhi[0][0], a0, 0, 0, 0);
            a1 = MFMA(Al0.v, Bhi[1][0], a1, 0, 0, 0);
            a2 = MFMA(Al0.v, Bhi[2][0], a2, 0, 0, 0);
            a3 = MFMA(Al0.v, Bhi[3][0], a3, 0, 0, 0);
            // kc = 1
            a0 = MFMA(Ah1.v, Bhi[0][1], a0, 0, 0, 0);
            a1 = MFMA(Ah1.v, Bhi[1][1], a1, 0, 0, 0);
            a2 = MFMA(Ah1.v, Bhi[2][1], a2, 0, 0, 0);
            a3 = MFMA(Ah1.v, Bhi[3][1], a3, 0, 0, 0);
            a0 = MFMA(Ah1.v, Blo[0][1], a0, 0, 0, 0);
            a1 = MFMA(Ah1.v, Blo[1][1], a1, 0, 0, 0);
            a2 = MFMA(Ah1.v, Blo[2][1], a2, 0, 0, 0);
            a3 = MFMA(Ah1.v, Blo[3][1], a3, 0, 0, 0);
            a0 = MFMA(Al1.v, Bhi[0][1], a0, 0, 0, 0);
            a1 = MFMA(Al1.v, Bhi[1][1], a1, 0, 0, 0);
            a2 = MFMA(Al1.v, Bhi[2][1], a2, 0, 0, 0);
            a3 = MFMA(Al1.v, Bhi[3][1], a3, 0, 0, 0);

            // Epilogue for h = m*16 + q*4 + r (a0=s0pre, a1=u0, a2=u1, a3=u2)
#pragma unroll
            for (int r = 0; r < 4; ++r) {
                const float4 lut = sLUT[m * 16 + q * 4 + r];
                const float s0 = a0[r] + lut.x;
                const float th = tanh_fast(s0);
                const float d2 = fmaf(-th, th, 1.0f);
                const float e0 = lut.y * d2, e1 = lut.z * d2, e2 = lut.w * d2;
                c0 = fmaf(e2, a2[r], c0); c0 = fmaf(-e1, a3[r], c0);
                c1 = fmaf(e0, a3[r], c1); c1 = fmaf(-e2, a1[r], c1);
                c2 = fmaf(e1, a1[r], c2); c2 = fmaf(-e0, a2[r], c2);
            }
        }

        // Reduce partial curls over the 4 h-subgroups (q dimension).
        c0 += __shfl_xor(c0, 16); c0 += __shfl_xor(c0, 32);
        c1 += __shfl_xor(c1, 16); c1 += __shfl_xor(c1, 32);
        c2 += __shfl_xor(c2, 16); c2 += __shfl_xor(c2, 32);

        // Coalesced store: lane (p,q<3) writes component q of point p ->
        // 48 contiguous dwords per tile.
        if (q < 3 && id < npts) {
            const float cv = (q == 0) ? c0 : ((q == 1) ? c1 : c2);
            out[tile * (NPT * 3) + p * 3 + q] = cv;
        }
    }
}

extern "C" void kernel_launch(void* const* d_in, const int* in_sizes, int n_in,
                              void* d_out, int out_size, void* d_ws, size_t ws_size,
                              hipStream_t stream) {
    const float* x  = (const float*)d_in[0];
    const float* W1 = (const float*)d_in[1];
    const float* b1 = (const float*)d_in[2];
    const float* W2 = (const float*)d_in[3];
    const float* b2 = (const float*)d_in[4];
    const float* W3 = (const float*)d_in[5];
    // d_in[6] (b3) unused: it cancels in the Jacobian.
    float* out = (float*)d_out;

    const int npts   = in_sizes[0] / 3;
    const int ntiles = (npts + NPT - 1) / NPT;
    int blocks = (ntiles + NWAVE - 1) / NWAVE;
    if (blocks > MAXB) blocks = MAXB;
    const int nw    = blocks * NWAVE;
    const int iters = (ntiles + nw - 1) / nw;

    hipLaunchKernelGGL(curl_mfma, dim3(blocks), dim3(BLK), 0, stream,
                       x, W1, b1, W2, b2, W3, out, npts, iters, ntiles);
}